// Round 4
// baseline (304.213 us; speedup 1.0000x reference)
//
#include <hip/hip_runtime.h>
#include <hip/hip_bf16.h>

#define B_    128
#define N_    196
#define HDIM  512
#define VDIM  2048
#define ATT   512
#define M_TOT (B_ * N_)   // 25088

#define BM  128    // rows per GEMM block
#define BKK 64     // K step (64 bf16 = 128B)
#define BN  128    // ATT cols per GEMM block (4 chunks)
#define NT  (VDIM / BKK)   // 32 K-steps
#define LDA 72     // padded A row length (bf16 elems): 144B rows

typedef float  f32x4  __attribute__((ext_vector_type(4)));
typedef __bf16 bf16x8 __attribute__((ext_vector_type(8)));

__device__ __forceinline__ void gload_lds16(const void* g, void* l) {
    __builtin_amdgcn_global_load_lds(
        (const __attribute__((address_space(1))) void*)g,
        (__attribute__((address_space(3))) void*)l, 16, 0, 0);
}

__device__ __forceinline__ float fast_tanh(float x) {
    float ax = fabsf(x);
    float e  = __expf(-2.f * ax);          // in (0,1], no overflow
    float t  = (1.f - e) / (1.f + e);
    return copysignf(t, x);
}

// ---------------------------------------------------------------------------
// Kernel P (merged prep): blocks 0..255 transpose Uw -> UwT bf16;
// blocks 256..383 compute whp = h@Ww + Wb + Ub.
// ---------------------------------------------------------------------------
__global__ void k_prep(const float* __restrict__ Uw, __bf16* __restrict__ UwT,
                       const float* __restrict__ h, const float* __restrict__ Ww,
                       const float* __restrict__ Wb, const float* __restrict__ Ub,
                       float* __restrict__ whp) {
    int t = threadIdx.x;  // 256
    if (blockIdx.x < 256) {
        __shared__ __bf16 st[64][65];
        int k0 = (blockIdx.x & 31) * 64;   // VDIM/64 = 32
        int c0 = (blockIdx.x >> 5) * 64;   // ATT/64  = 8
#pragma unroll
        for (int i = 0; i < 16; ++i) {
            int lin = i * 256 + t;
            int kk = lin >> 6, cc = lin & 63;
            st[kk][cc] = (__bf16)Uw[(size_t)(k0 + kk) * ATT + c0 + cc];
        }
        __syncthreads();
#pragma unroll
        for (int i = 0; i < 16; ++i) {
            int lin = i * 256 + t;
            int cc = lin >> 6, kk = lin & 63;
            UwT[(size_t)(c0 + cc) * VDIM + k0 + kk] = st[kk][cc];
        }
    } else {
        __shared__ float hs[HDIM];
        int b = blockIdx.x - 256;          // 0..127
        hs[t]       = h[(size_t)b * HDIM + t];
        hs[t + 256] = h[(size_t)b * HDIM + t + 256];
        __syncthreads();
        float acc0 = 0.f, acc1 = 0.f;
        for (int k = 0; k < HDIM; ++k) {
            float hv = hs[k];
            acc0 += hv * Ww[(size_t)k * ATT + t];
            acc1 += hv * Ww[(size_t)k * ATT + t + 256];
        }
        whp[(size_t)b * ATT + t]       = acc0 + Wb[t] + Ub[t];
        whp[(size_t)b * ATT + t + 256] = acc1 + Wb[t + 256] + Ub[t + 256];
    }
}

// ---------------------------------------------------------------------------
// Kernel G: 128x128 tile, BK=64, 4 waves, double-buffered.
// A: fp32 V reg-staged (load -> cvt -> padded ds_write), T14-ordered.
//    cc==0 blocks also store the converted bf16 tile to Vb (for k_ctx).
// B: bf16 UwT via global_load_lds, XOR-swizzled (pre-swizzled source).
// Epilogue: e_part[cc][m] = sum_cols tanh(acc+whp)*vw.
// Grid: 784 blocks 1D, XCD-bijective swizzle -> (mtile, cc); the 4 cc-blocks
// of an mtile land on one XCD and stream K in lockstep -> A fetched ~once.
// ---------------------------------------------------------------------------
template <bool WRITE_VB>
__global__ __launch_bounds__(256, 2) void k_scores(
    const float* __restrict__ Vf, __bf16* __restrict__ Vb,
    const __bf16* __restrict__ UwT, const float* __restrict__ whp,
    const float* __restrict__ vw, float* __restrict__ e_part)
{
    __shared__ __align__(16) __bf16 As[2][BM][LDA];   // 2 x 18 KB (padded)
    __shared__ __align__(16) __bf16 Bs[2][BN][BKK];   // 2 x 16 KB (linear+XOR)
    __shared__ float red[2][BM];

    int bid = blockIdx.x;
    int lid = (bid & 7) * (784 / 8) + (bid >> 3);
    int mtile = lid >> 2;         // 0..195
    int cc    = lid & 3;          // 0..3
    int m0 = mtile * BM;
    int c0 = cc * BN;
    int t    = threadIdx.x;
    int lane = t & 63;
    int wave = t >> 6;
    int wr = wave >> 1;           // row half (64 rows)
    int wc = wave & 1;            // col half (64 cols)

    f32x4 acc[4][4];
#pragma unroll
    for (int i = 0; i < 4; ++i)
#pragma unroll
        for (int j = 0; j < 4; ++j) acc[i][j] = (f32x4){0.f, 0.f, 0.f, 0.f};

    // ---- B staging (gload_lds: linear dest, pre-swizzled source) ----
    int lr  = lane >> 3;                         // 0..7
    int csw = ((lane & 7) ^ (lr & 7)) * 8;       // swizzled source chunk
    const __bf16* BgS = UwT + (size_t)(c0 + wave * 32 + lr) * VDIM + csw;
    __bf16* Bl0 = &Bs[0][wave * 32 + lr][(lane & 7) * 8];  // linear dest

    // ---- A staging (reg: fp32 load -> cvt -> padded ds_write) ----
    int ra = t >> 1;              // 0..127 row
    int ka = (t & 1) * 32;        // 0 or 32 floats
    const float*  Af  = Vf + (size_t)(m0 + ra) * VDIM + ka;
    __bf16*       VbR = WRITE_VB ? (Vb + (size_t)(m0 + ra) * VDIM) : nullptr;
    const bool    do_store = WRITE_VB && (cc == 0);

    float4 aA[8];

#define A_LOAD(kt)                                                              \
    do {                                                                        \
        const float4* src = reinterpret_cast<const float4*>(Af + (kt) * BKK);   \
        _Pragma("unroll")                                                       \
        for (int i = 0; i < 8; ++i) aA[i] = src[i];                             \
    } while (0)

#define B_GLOAD(buf, kt)                                                        \
    do {                                                                        \
        _Pragma("unroll")                                                       \
        for (int i = 0; i < 4; ++i)                                             \
            gload_lds16(BgS + (kt) * BKK + (size_t)i * 8 * VDIM,                \
                        Bl0 + (buf) * (BN * BKK) + i * 8 * BKK);                \
    } while (0)

#define A_WRITE(buf, kt)                                                        \
    do {                                                                        \
        _Pragma("unroll")                                                       \
        for (int i = 0; i < 4; ++i) {                                           \
            float4 x = aA[2 * i], y = aA[2 * i + 1];                            \
            bf16x8 w;                                                           \
            w[0] = (__bf16)x.x; w[1] = (__bf16)x.y;                             \
            w[2] = (__bf16)x.z; w[3] = (__bf16)x.w;                             \
            w[4] = (__bf16)y.x; w[5] = (__bf16)y.y;                             \
            w[6] = (__bf16)y.z; w[7] = (__bf16)y.w;                             \
            int ch = (t & 1) * 4 + i;                                           \
            *reinterpret_cast<bf16x8*>(&As[buf][ra][ch * 8]) = w;               \
            if (do_store)                                                       \
                *reinterpret_cast<bf16x8*>(VbR + (kt) * BKK + ch * 8) = w;      \
        }                                                                       \
    } while (0)

    int lcol = lane & 15;
    int lg4  = lane >> 4;
    int arow_base = wr * 64;
    int bcol_base = wc * 64;

    // prologue
    A_LOAD(0);
    B_GLOAD(0, 0);
    A_WRITE(0, 0);
    __syncthreads();

    for (int kt = 0; kt < NT; ++kt) {
        int buf = kt & 1;
        bool pf = (kt + 1 < NT);
        if (pf) {
            A_LOAD(kt + 1);           // issue early (latency hides under MFMA)
            B_GLOAD(buf ^ 1, kt + 1);
        }
        // compute current tile
#pragma unroll
        for (int ks = 0; ks < 2; ++ks) {
            bf16x8 af[4], bfr[4];
#pragma unroll
            for (int i = 0; i < 4; ++i) {
                int row = arow_base + i * 16 + lcol;
                af[i] = *reinterpret_cast<const bf16x8*>(&As[buf][row][ks * 32 + lg4 * 8]);
            }
#pragma unroll
            for (int j = 0; j < 4; ++j) {
                int row = bcol_base + j * 16 + lcol;
                int ch  = ((ks * 4 + lg4) ^ (row & 7)) * 8;
                bfr[j] = *reinterpret_cast<const bf16x8*>(&Bs[buf][row][ch]);
            }
            __builtin_amdgcn_s_setprio(1);
#pragma unroll
            for (int i = 0; i < 4; ++i)
#pragma unroll
                for (int j = 0; j < 4; ++j)
                    acc[i][j] = __builtin_amdgcn_mfma_f32_16x16x32_bf16(af[i], bfr[j], acc[i][j], 0, 0, 0);
            __builtin_amdgcn_s_setprio(0);
        }
        if (pf) A_WRITE(buf ^ 1, kt + 1);   // cvt + LDS write (+Vb store)
        __syncthreads();
    }
#undef A_LOAD
#undef B_GLOAD
#undef A_WRITE

    // ---- epilogue: rowsum over this block's 128 cols ----
    int lrow4 = lg4 * 4;
    float rowsum[4][4];
#pragma unroll
    for (int i = 0; i < 4; ++i)
#pragma unroll
        for (int r = 0; r < 4; ++r) rowsum[i][r] = 0.f;

#pragma unroll
    for (int j = 0; j < 4; ++j) {
        int col = c0 + wc * 64 + j * 16 + lcol;
        float vwv = vw[col];
#pragma unroll
        for (int i = 0; i < 4; ++i) {
#pragma unroll
            for (int r = 0; r < 4; ++r) {
                int m = m0 + wr * 64 + i * 16 + lrow4 + r;
                int b = m / N_;
                float x = acc[i][j][r] + whp[(size_t)b * ATT + col];
                rowsum[i][r] += fast_tanh(x) * vwv;
            }
        }
    }
#pragma unroll
    for (int i = 0; i < 4; ++i) {
#pragma unroll
        for (int r = 0; r < 4; ++r) {
            float v = rowsum[i][r];
            v += __shfl_xor(v, 1);
            v += __shfl_xor(v, 2);
            v += __shfl_xor(v, 4);
            v += __shfl_xor(v, 8);
            if (lcol == 0)
                red[wc][wr * 64 + i * 16 + lrow4 + r] = v;
        }
    }
    __syncthreads();
    if (t < BM)
        e_part[(size_t)cc * M_TOT + m0 + t] = red[0][t] + red[1][t];
}

// ---------------------------------------------------------------------------
// Kernel S: softmax over N=196 per batch; writes a -> d_out tail
// ---------------------------------------------------------------------------
__global__ void k_softmax(const float* __restrict__ e_part, const float* __restrict__ vb,
                          float* __restrict__ a_out) {
    int b = blockIdx.x;
    int t = threadIdx.x;  // 256
    __shared__ float sm[256];
    float ev = 0.f;
    float e  = -1e30f;
    if (t < N_) {
        int m = b * N_ + t;
        ev = e_part[m] + e_part[M_TOT + m] + e_part[2 * M_TOT + m] + e_part[3 * M_TOT + m] + vb[0];
        e = ev;
    }
    sm[t] = e;
    __syncthreads();
    for (int s = 128; s > 0; s >>= 1) {
        if (t < s) sm[t] = fmaxf(sm[t], sm[t + s]);
        __syncthreads();
    }
    float mx = sm[0];
    __syncthreads();
    float ex = (t < N_) ? __expf(ev - mx) : 0.f;
    sm[t] = ex;
    __syncthreads();
    for (int s = 128; s > 0; s >>= 1) {
        if (t < s) sm[t] += sm[t + s];
        __syncthreads();
    }
    float inv = 1.f / sm[0];
    if (t < N_) a_out[(size_t)b * N_ + t] = ex * inv;
}

// ---------------------------------------------------------------------------
// Kernel C: ctx[b][v] = sum_n a[b][n] * V[b][n][v]
// ---------------------------------------------------------------------------
__global__ void k_ctx_bf(const __bf16* __restrict__ Vb, const float* __restrict__ a,
                         float* __restrict__ ctx) {
    int b  = blockIdx.x;   // 128
    int ch = blockIdx.y;   // 2 chunks of 1024 cols
    int t  = threadIdx.x;  // 128
    __shared__ float as_[N_];
    for (int i = t; i < N_; i += 128) as_[i] = a[(size_t)b * N_ + i];
    __syncthreads();
    int col = ch * 1024 + t * 8;
    const __bf16* Vp = Vb + (size_t)b * N_ * VDIM + col;
    float av[8] = {0.f, 0.f, 0.f, 0.f, 0.f, 0.f, 0.f, 0.f};
    for (int n = 0; n < N_; ++n) {
        bf16x8 v = *reinterpret_cast<const bf16x8*>(Vp + (size_t)n * VDIM);
        float an = as_[n];
#pragma unroll
        for (int j = 0; j < 8; ++j) av[j] += an * (float)v[j];
    }
    f32x4 lo = {av[0], av[1], av[2], av[3]};
    f32x4 hi = {av[4], av[5], av[6], av[7]};
    f32x4* dst = reinterpret_cast<f32x4*>(ctx + (size_t)b * VDIM + col);
    dst[0] = lo;
    dst[1] = hi;
}

__global__ void k_ctx_f32(const float* __restrict__ V, const float* __restrict__ a,
                          float* __restrict__ ctx) {
    int b  = blockIdx.x;
    int ch = blockIdx.y;
    int t  = threadIdx.x;  // 128
    __shared__ float as_[N_];
    for (int i = t; i < N_; i += 128) as_[i] = a[(size_t)b * N_ + i];
    __syncthreads();
    int col = ch * 512 + t * 4;
    const f32x4* Vp = reinterpret_cast<const f32x4*>(V + (size_t)b * N_ * VDIM + col);
    f32x4 accv = {0.f, 0.f, 0.f, 0.f};
    for (int n = 0; n < N_; ++n)
        accv += as_[n] * Vp[(size_t)n * (VDIM / 4)];
    *reinterpret_cast<f32x4*>(ctx + (size_t)b * VDIM + col) = accv;
}

// ---------------------------------------------------------------------------
extern "C" void kernel_launch(void* const* d_in, const int* in_sizes, int n_in,
                              void* d_out, int out_size, void* d_ws, size_t ws_size,
                              hipStream_t stream) {
    const float* h  = (const float*)d_in[0];
    const float* V  = (const float*)d_in[1];
    const float* Ww = (const float*)d_in[2];
    const float* Wb = (const float*)d_in[3];
    const float* Uw = (const float*)d_in[4];
    const float* Ub = (const float*)d_in[5];
    const float* vw = (const float*)d_in[6];
    const float* vb = (const float*)d_in[7];

    float* out     = (float*)d_out;
    float* ctx_out = out;                        // B*VDIM floats
    float* a_out   = out + (size_t)B_ * VDIM;    // B*N floats

    const size_t vb_bytes = (size_t)B_ * N_ * VDIM * sizeof(__bf16);  // ~103 MB
    const size_t tail     = 2u * 1024 * 1024 + 256 * 1024 + (size_t)4 * M_TOT * 4 + 4096;
    bool write_vb = ws_size >= vb_bytes + tail;

    char*   ws   = (char*)d_ws;
    __bf16* Vb   = (__bf16*)ws;
    char*   rest = ws + (write_vb ? vb_bytes : 0);
    __bf16* UwT   = (__bf16*)rest;
    float*  whp   = (float*)(rest + 2u * 1024 * 1024);
    float*  e_prt = (float*)(rest + 2u * 1024 * 1024 + 256 * 1024);

    k_prep<<<dim3(384), 256, 0, stream>>>(Uw, UwT, h, Ww, Wb, Ub, whp);
    if (write_vb)
        k_scores<true><<<dim3(784), 256, 0, stream>>>(V, Vb, UwT, whp, vw, e_prt);
    else
        k_scores<false><<<dim3(784), 256, 0, stream>>>(V, Vb, UwT, whp, vw, e_prt);
    k_softmax<<<dim3(B_), 256, 0, stream>>>(e_prt, vb, a_out);
    if (write_vb)
        k_ctx_bf<<<dim3(B_, 2), 128, 0, stream>>>(Vb, a_out, ctx_out);
    else
        k_ctx_f32<<<dim3(B_, 4), 128, 0, stream>>>(V, a_out, ctx_out);
}

// Round 5
// 185.847 us; speedup vs baseline: 1.6369x; 1.6369x over previous
//
#include <hip/hip_runtime.h>
#include <hip/hip_bf16.h>

#define B_    128
#define N_    196
#define HDIM  512
#define VDIM  2048
#define ATT   512
#define M_TOT (B_ * N_)   // 25088

#define BKK 64             // K step (64 bf16 = 128B = 8 chunks of 16B)
#define NT  (VDIM / BKK)   // 32 K-steps

#define BM2 256            // main tile
#define BN2 256
#define BM1 128            // fallback tile
#define BN1 128

typedef float  f32x4  __attribute__((ext_vector_type(4)));
typedef __bf16 bf16x8 __attribute__((ext_vector_type(8)));
typedef __bf16 bf16x4 __attribute__((ext_vector_type(4)));

__device__ __forceinline__ void gload_lds16(const void* g, void* l) {
    __builtin_amdgcn_global_load_lds(
        (const __attribute__((address_space(1))) void*)g,
        (__attribute__((address_space(3))) void*)l, 16, 0, 0);
}

__device__ __forceinline__ float fast_tanh(float x) {
    float ax = fabsf(x);
    float e  = __expf(-2.f * ax);          // in (0,1], no overflow
    float t  = (1.f - e) / (1.f + e);
    return copysignf(t, x);
}

// ---------------------------------------------------------------------------
// Kernel CV: V fp32 -> bf16 (streaming)  [measured ~49us, HBM roofline]
// ---------------------------------------------------------------------------
__global__ void k_conv(const float* __restrict__ V, __bf16* __restrict__ Vb, int n8) {
    int idx    = blockIdx.x * blockDim.x + threadIdx.x;
    int stride = gridDim.x * blockDim.x;
    for (int i = idx; i < n8; i += stride) {
        const float4* s = reinterpret_cast<const float4*>(V + (size_t)i * 8);
        float4 x = s[0], y = s[1];
        bf16x8 w;
        w[0] = (__bf16)x.x; w[1] = (__bf16)x.y; w[2] = (__bf16)x.z; w[3] = (__bf16)x.w;
        w[4] = (__bf16)y.x; w[5] = (__bf16)y.y; w[6] = (__bf16)y.z; w[7] = (__bf16)y.w;
        reinterpret_cast<bf16x8*>(Vb)[i] = w;
    }
}

// ---------------------------------------------------------------------------
// Kernel P (merged prep): blocks 0..255 transpose Uw -> UwT bf16;
// blocks 256..383 compute whp = h@Ww + Wb + Ub.
// ---------------------------------------------------------------------------
__global__ void k_prep(const float* __restrict__ Uw, __bf16* __restrict__ UwT,
                       const float* __restrict__ h, const float* __restrict__ Ww,
                       const float* __restrict__ Wb, const float* __restrict__ Ub,
                       float* __restrict__ whp) {
    int t = threadIdx.x;  // 256
    if (blockIdx.x < 256) {
        __shared__ __bf16 st[64][65];
        int k0 = (blockIdx.x & 31) * 64;
        int c0 = (blockIdx.x >> 5) * 64;
#pragma unroll
        for (int i = 0; i < 16; ++i) {
            int lin = i * 256 + t;
            int kk = lin >> 6, cc = lin & 63;
            st[kk][cc] = (__bf16)Uw[(size_t)(k0 + kk) * ATT + c0 + cc];
        }
        __syncthreads();
#pragma unroll
        for (int i = 0; i < 16; ++i) {
            int lin = i * 256 + t;
            int cc = lin >> 6, kk = lin & 63;
            UwT[(size_t)(c0 + cc) * VDIM + k0 + kk] = st[kk][cc];
        }
    } else {
        __shared__ float hs[HDIM];
        int b = blockIdx.x - 256;
        hs[t]       = h[(size_t)b * HDIM + t];
        hs[t + 256] = h[(size_t)b * HDIM + t + 256];
        __syncthreads();
        float acc0 = 0.f, acc1 = 0.f;
        for (int k = 0; k < HDIM; ++k) {
            float hv = hs[k];
            acc0 += hv * Ww[(size_t)k * ATT + t];
            acc1 += hv * Ww[(size_t)k * ATT + t + 256];
        }
        whp[(size_t)b * ATT + t]       = acc0 + Wb[t] + Ub[t];
        whp[(size_t)b * ATT + t + 256] = acc1 + Wb[t + 256] + Ub[t + 256];
    }
}

// ---------------------------------------------------------------------------
// Kernel G (main): 256x256 tile, BK=64, 8 waves (2 row-halves x 4 col-
// quarters, 128x64 per wave), double-buffered, all staging via
// global_load_lds with XOR-swizzle (pre-swizzled source, linear dest,
// swizzled ds_read). Grid: 196 blocks = single round, 1 block/CU.
// Epilogue: e_part[cc][m] = sum over 256 cols of tanh(acc+whp)*vw.
// ---------------------------------------------------------------------------
__global__ __launch_bounds__(512, 2) void k_scores256(
    const __bf16* __restrict__ Vb, const __bf16* __restrict__ UwT,
    const float* __restrict__ whp, const float* __restrict__ vw,
    float* __restrict__ e_part)
{
    __shared__ __align__(16) __bf16 As[2][BM2][BKK];   // 64 KB
    __shared__ __align__(16) __bf16 Bs[2][BN2][BKK];   // 64 KB
    __shared__ float red[4][BM2];                      // 4 KB

    // bijective XCD swizzle for 196 blocks (196 = 8*24 + 4; m204 formula)
    int bid = blockIdx.x;
    int xcd = bid & 7, ix = bid >> 3;
    int lid = (xcd < 4 ? xcd * 25 : 100 + (xcd - 4) * 24) + ix;
    int mtile = lid >> 1;         // 0..97
    int cc    = lid & 1;          // 0..1
    int m0 = mtile * BM2;
    int c0 = cc * BN2;

    int t    = threadIdx.x;       // 0..511
    int lane = t & 63;
    int wave = t >> 6;            // 0..7
    int wr = wave >> 2;           // 0..1 : row half (128 rows)
    int wc = wave & 3;            // 0..3 : col quarter (64 cols)

    f32x4 acc[8][4];
#pragma unroll
    for (int i = 0; i < 8; ++i)
#pragma unroll
        for (int j = 0; j < 4; ++j) acc[i][j] = (f32x4){0.f, 0.f, 0.f, 0.f};

    // staging: wave w round i covers rows [w*32 + i*8, +8); lane -> (row, chunk).
    // LDS[row][c] holds global chunk c ^ (row&7); dest linear -> source chunk
    // = (lane&7) ^ lr  (row&7 == lr since rows step by 8).
    int lr  = lane >> 3;                       // 0..7
    int csw = ((lane & 7) ^ lr) * 8;           // pre-swizzled source elem offset
    const __bf16* AgS = Vb  + (size_t)(m0 + wave * 32 + lr) * VDIM + csw;
    const __bf16* BgS = UwT + (size_t)(c0 + wave * 32 + lr) * VDIM + csw;
    __bf16* Al0 = &As[0][wave * 32 + lr][(lane & 7) * 8];
    __bf16* Bl0 = &Bs[0][wave * 32 + lr][(lane & 7) * 8];

#define STAGE2(buf, kt)                                                         \
    do {                                                                        \
        _Pragma("unroll")                                                       \
        for (int i = 0; i < 4; ++i) {                                           \
            gload_lds16(AgS + (kt) * BKK + (size_t)i * 8 * VDIM,                \
                        Al0 + (buf) * (BM2 * BKK) + i * 8 * BKK);               \
            gload_lds16(BgS + (kt) * BKK + (size_t)i * 8 * VDIM,                \
                        Bl0 + (buf) * (BN2 * BKK) + i * 8 * BKK);               \
        }                                                                       \
    } while (0)

    int lcol = lane & 15;
    int lg4  = lane >> 4;
    int arow0 = wr * 128;
    int bcol0 = wc * 64;

    STAGE2(0, 0);
    __syncthreads();

    for (int kt = 0; kt < NT; ++kt) {
        int buf = kt & 1;
        if (kt + 1 < NT) STAGE2(buf ^ 1, kt + 1);   // async prefetch next tile
#pragma unroll
        for (int ks = 0; ks < 2; ++ks) {
            bf16x8 bfr[4], af[8];
#pragma unroll
            for (int j = 0; j < 4; ++j) {
                int row = bcol0 + j * 16 + lcol;
                int ch  = ((ks * 4 + lg4) ^ (row & 7)) * 8;
                bfr[j] = *reinterpret_cast<const bf16x8*>(&Bs[buf][row][ch]);
            }
#pragma unroll
            for (int i = 0; i < 8; ++i) {
                int row = arow0 + i * 16 + lcol;
                int ch  = ((ks * 4 + lg4) ^ (row & 7)) * 8;
                af[i] = *reinterpret_cast<const bf16x8*>(&As[buf][row][ch]);
            }
            __builtin_amdgcn_s_setprio(1);
#pragma unroll
            for (int i = 0; i < 8; ++i)
#pragma unroll
                for (int j = 0; j < 4; ++j)
                    acc[i][j] = __builtin_amdgcn_mfma_f32_16x16x32_bf16(af[i], bfr[j], acc[i][j], 0, 0, 0);
            __builtin_amdgcn_s_setprio(0);
        }
        __syncthreads();   // drains prefetch (vmcnt0) + protects buf swap
    }
#undef STAGE2

    // ---- epilogue: rowsum over this block's 256 cols ----
    int lrow4 = lg4 * 4;
#pragma unroll
    for (int i = 0; i < 8; ++i) {
        float rs[4] = {0.f, 0.f, 0.f, 0.f};
#pragma unroll
        for (int j = 0; j < 4; ++j) {
            int col = c0 + wc * 64 + j * 16 + lcol;
            float vwv = vw[col];
#pragma unroll
            for (int r = 0; r < 4; ++r) {
                int m = m0 + wr * 128 + i * 16 + lrow4 + r;
                int b = m / N_;
                float x = acc[i][j][r] + whp[(size_t)b * ATT + col];
                rs[r] += fast_tanh(x) * vwv;
            }
        }
#pragma unroll
        for (int r = 0; r < 4; ++r) {
            float v = rs[r];
            v += __shfl_xor(v, 1);
            v += __shfl_xor(v, 2);
            v += __shfl_xor(v, 4);
            v += __shfl_xor(v, 8);
            if (lcol == 0)
                red[wc][wr * 128 + i * 16 + lrow4 + r] = v;
        }
    }
    __syncthreads();
    if (t < BM2)
        e_part[(size_t)cc * M_TOT + m0 + t] =
            red[0][t] + red[1][t] + red[2][t] + red[3][t];
}

// ---------------------------------------------------------------------------
// Kernel G (fallback, no-ws path): R3-proven 128x128, 4 waves, fp32 A
// reg-staged with XOR ds_write; B via gload_lds XOR. Writes 4 partials.
// ---------------------------------------------------------------------------
__global__ __launch_bounds__(256, 2) void k_scores_small(
    const float* __restrict__ Vf, const __bf16* __restrict__ UwT,
    const float* __restrict__ whp, const float* __restrict__ vw,
    float* __restrict__ e_part)
{
    __shared__ __align__(16) __bf16 As[2][BM1][BKK];
    __shared__ __align__(16) __bf16 Bs[2][BN1][BKK];
    __shared__ float red[2][BM1];

    int bid = blockIdx.x;
    int lid = (bid & 7) * (784 / 8) + (bid >> 3);
    int mtile = lid >> 2;
    int cc    = lid & 3;
    int m0 = mtile * BM1;
    int c0 = cc * BN1;
    int t    = threadIdx.x;
    int lane = t & 63;
    int wave = t >> 6;
    int wr = wave >> 1;
    int wc = wave & 1;

    f32x4 acc[4][4];
#pragma unroll
    for (int i = 0; i < 4; ++i)
#pragma unroll
        for (int j = 0; j < 4; ++j) acc[i][j] = (f32x4){0.f, 0.f, 0.f, 0.f};

    int lr  = lane >> 3;
    int csw = ((lane & 7) ^ lr) * 8;
    const __bf16* BgS = UwT + (size_t)(c0 + wave * 32 + lr) * VDIM + csw;
    __bf16* Bl0 = &Bs[0][wave * 32 + lr][(lane & 7) * 8];

    int ra = t >> 1;
    int ka = (t & 1) * 32;
    const float* Af = Vf + (size_t)(m0 + ra) * VDIM + ka;

#define STAGE1(buf, kt)                                                         \
    do {                                                                        \
        _Pragma("unroll")                                                       \
        for (int i = 0; i < 4; ++i)                                             \
            gload_lds16(BgS + (kt) * BKK + (size_t)i * 8 * VDIM,                \
                        Bl0 + (buf) * (BN1 * BKK) + i * 8 * BKK);               \
        const float4* src = reinterpret_cast<const float4*>(Af + (kt) * BKK);   \
        _Pragma("unroll")                                                       \
        for (int i = 0; i < 4; ++i) {                                           \
            float4 x = src[2 * i];                                              \
            float4 y = src[2 * i + 1];                                          \
            bf16x8 w;                                                           \
            w[0] = (__bf16)x.x; w[1] = (__bf16)x.y;                             \
            w[2] = (__bf16)x.z; w[3] = (__bf16)x.w;                             \
            w[4] = (__bf16)y.x; w[5] = (__bf16)y.y;                             \
            w[6] = (__bf16)y.z; w[7] = (__bf16)y.w;                             \
            int ch = (((t & 1) * 4 + i) ^ (ra & 7)) * 8;                        \
            *reinterpret_cast<bf16x8*>(&As[buf][ra][ch]) = w;                   \
        }                                                                       \
    } while (0)

    int lcol = lane & 15;
    int lg4  = lane >> 4;
    int arow0 = wr * 64;
    int bcol0 = wc * 64;

    STAGE1(0, 0);
    __syncthreads();

    for (int kt = 0; kt < NT; ++kt) {
        int buf = kt & 1;
        if (kt + 1 < NT) STAGE1(buf ^ 1, kt + 1);
#pragma unroll
        for (int ks = 0; ks < 2; ++ks) {
            bf16x8 af[4], bfr[4];
#pragma unroll
            for (int i = 0; i < 4; ++i) {
                int row = arow0 + i * 16 + lcol;
                int ch  = ((ks * 4 + lg4) ^ (row & 7)) * 8;
                af[i] = *reinterpret_cast<const bf16x8*>(&As[buf][row][ch]);
            }
#pragma unroll
            for (int j = 0; j < 4; ++j) {
                int row = bcol0 + j * 16 + lcol;
                int ch  = ((ks * 4 + lg4) ^ (row & 7)) * 8;
                bfr[j] = *reinterpret_cast<const bf16x8*>(&Bs[buf][row][ch]);
            }
#pragma unroll
            for (int i = 0; i < 4; ++i)
#pragma unroll
                for (int j = 0; j < 4; ++j)
                    acc[i][j] = __builtin_amdgcn_mfma_f32_16x16x32_bf16(af[i], bfr[j], acc[i][j], 0, 0, 0);
        }
        __syncthreads();
    }
#undef STAGE1

    int lrow4 = lg4 * 4;
#pragma unroll
    for (int i = 0; i < 4; ++i) {
        float rs[4] = {0.f, 0.f, 0.f, 0.f};
#pragma unroll
        for (int j = 0; j < 4; ++j) {
            int col = c0 + wc * 64 + j * 16 + lcol;
            float vwv = vw[col];
#pragma unroll
            for (int r = 0; r < 4; ++r) {
                int m = m0 + wr * 64 + i * 16 + lrow4 + r;
                int b = m / N_;
                float x = acc[i][j][r] + whp[(size_t)b * ATT + col];
                rs[r] += fast_tanh(x) * vwv;
            }
        }
#pragma unroll
        for (int r = 0; r < 4; ++r) {
            float v = rs[r];
            v += __shfl_xor(v, 1);
            v += __shfl_xor(v, 2);
            v += __shfl_xor(v, 4);
            v += __shfl_xor(v, 8);
            if (lcol == 0)
                red[wc][wr * 64 + i * 16 + lrow4 + r] = v;
        }
    }
    __syncthreads();
    if (t < BM1)
        e_part[(size_t)cc * M_TOT + m0 + t] = red[0][t] + red[1][t];
}

// ---------------------------------------------------------------------------
// Kernel S: softmax over N=196 per batch (npart partial score arrays)
// ---------------------------------------------------------------------------
__global__ void k_softmax(const float* __restrict__ e_part, const float* __restrict__ vb,
                          float* __restrict__ a_out, int npart) {
    int b = blockIdx.x;
    int t = threadIdx.x;  // 256
    __shared__ float sm[256];
    float ev = 0.f;
    float e  = -1e30f;
    if (t < N_) {
        int m = b * N_ + t;
        ev = vb[0];
        for (int p = 0; p < npart; ++p) ev += e_part[(size_t)p * M_TOT + m];
        e = ev;
    }
    sm[t] = e;
    __syncthreads();
    for (int s = 128; s > 0; s >>= 1) {
        if (t < s) sm[t] = fmaxf(sm[t], sm[t + s]);
        __syncthreads();
    }
    float mx = sm[0];
    __syncthreads();
    float ex = (t < N_) ? __expf(ev - mx) : 0.f;
    sm[t] = ex;
    __syncthreads();
    for (int s = 128; s > 0; s >>= 1) {
        if (t < s) sm[t] += sm[t + s];
        __syncthreads();
    }
    float inv = 1.f / sm[0];
    if (t < N_) a_out[(size_t)b * N_ + t] = ex * inv;
}

// ---------------------------------------------------------------------------
// Kernel C: ctx[b][v] = sum_n a[b][n] * V[b][n][v]
// ---------------------------------------------------------------------------
__global__ void k_ctx_bf(const __bf16* __restrict__ Vb, const float* __restrict__ a,
                         float* __restrict__ ctx) {
    int b  = blockIdx.x;   // 128
    int ch = blockIdx.y;   // 2 chunks of 1024 cols
    int t  = threadIdx.x;  // 128
    __shared__ float as_[N_];
    for (int i = t; i < N_; i += 128) as_[i] = a[(size_t)b * N_ + i];
    __syncthreads();
    int col = ch * 1024 + t * 8;
    const __bf16* Vp = Vb + (size_t)b * N_ * VDIM + col;
    float av[8] = {0.f, 0.f, 0.f, 0.f, 0.f, 0.f, 0.f, 0.f};
    for (int n = 0; n < N_; ++n) {
        bf16x8 v = *reinterpret_cast<const bf16x8*>(Vp + (size_t)n * VDIM);
        float an = as_[n];
#pragma unroll
        for (int j = 0; j < 8; ++j) av[j] += an * (float)v[j];
    }
    f32x4 lo = {av[0], av[1], av[2], av[3]};
    f32x4 hi = {av[4], av[5], av[6], av[7]};
    f32x4* dst = reinterpret_cast<f32x4*>(ctx + (size_t)b * VDIM + col);
    dst[0] = lo;
    dst[1] = hi;
}

__global__ void k_ctx_f32(const float* __restrict__ V, const float* __restrict__ a,
                          float* __restrict__ ctx) {
    int b  = blockIdx.x;
    int ch = blockIdx.y;
    int t  = threadIdx.x;  // 128
    __shared__ float as_[N_];
    for (int i = t; i < N_; i += 128) as_[i] = a[(size_t)b * N_ + i];
    __syncthreads();
    int col = ch * 512 + t * 4;
    const f32x4* Vp = reinterpret_cast<const f32x4*>(V + (size_t)b * N_ * VDIM + col);
    f32x4 accv = {0.f, 0.f, 0.f, 0.f};
    for (int n = 0; n < N_; ++n)
        accv += as_[n] * Vp[(size_t)n * (VDIM / 4)];
    *reinterpret_cast<f32x4*>(ctx + (size_t)b * VDIM + col) = accv;
}

// ---------------------------------------------------------------------------
extern "C" void kernel_launch(void* const* d_in, const int* in_sizes, int n_in,
                              void* d_out, int out_size, void* d_ws, size_t ws_size,
                              hipStream_t stream) {
    const float* h  = (const float*)d_in[0];
    const float* V  = (const float*)d_in[1];
    const float* Ww = (const float*)d_in[2];
    const float* Wb = (const float*)d_in[3];
    const float* Uw = (const float*)d_in[4];
    const float* Ub = (const float*)d_in[5];
    const float* vw = (const float*)d_in[6];
    const float* vb = (const float*)d_in[7];

    float* out     = (float*)d_out;
    float* ctx_out = out;                        // B*VDIM floats
    float* a_out   = out + (size_t)B_ * VDIM;    // B*N floats

    const size_t vb_bytes = (size_t)B_ * N_ * VDIM * sizeof(__bf16);  // ~103 MB
    const size_t tail     = 2u * 1024 * 1024 + 256 * 1024 + (size_t)4 * M_TOT * 4 + 4096;
    bool preconv = ws_size >= vb_bytes + tail;

    char*   ws   = (char*)d_ws;
    __bf16* Vb   = (__bf16*)ws;
    char*   rest = ws + (preconv ? vb_bytes : 0);
    __bf16* UwT   = (__bf16*)rest;
    float*  whp   = (float*)(rest + 2u * 1024 * 1024);
    float*  e_prt = (float*)(rest + 2u * 1024 * 1024 + 256 * 1024);

    k_prep<<<dim3(384), 256, 0, stream>>>(Uw, UwT, h, Ww, Wb, Ub, whp);
    if (preconv) {
        int n8 = (B_ * N_ * VDIM) / 8;
        k_conv<<<2048, 256, 0, stream>>>(V, Vb, n8);
        k_scores256<<<dim3(196), 512, 0, stream>>>(Vb, UwT, whp, vw, e_prt);
        k_softmax<<<dim3(B_), 256, 0, stream>>>(e_prt, vb, a_out, 2);
        k_ctx_bf<<<dim3(B_, 2), 128, 0, stream>>>(Vb, a_out, ctx_out);
    } else {
        k_scores_small<<<dim3(784), 256, 0, stream>>>(V, UwT, whp, vw, e_prt);
        k_softmax<<<dim3(B_), 256, 0, stream>>>(e_prt, vb, a_out, 4);
        k_ctx_f32<<<dim3(B_, 4), 128, 0, stream>>>(V, a_out, ctx_out);
    }
}

// Round 7
// 167.310 us; speedup vs baseline: 1.8183x; 1.1108x over previous
//
#include <hip/hip_runtime.h>
#include <hip/hip_bf16.h>

#define B_    128
#define N_    196
#define HDIM  512
#define VDIM  2048
#define ATT   512
#define M_TOT (B_ * N_)   // 25088

#define BKK 64             // K step (64 bf16 = 128B = 8 chunks of 16B)
#define NT  (VDIM / BKK)   // 32 K-steps
#define BM1 128
#define BN1 128
#define N8     ((B_ * N_ * VDIM) / 8)   // 6,422,528 float8 items
#define NCONVB 3136                      // conv blocks (grid-stride x8)

typedef float  f32x4  __attribute__((ext_vector_type(4)));
typedef __bf16 bf16x8 __attribute__((ext_vector_type(8)));

__device__ __forceinline__ void gload_lds16(const void* g, void* l) {
    __builtin_amdgcn_global_load_lds(
        (const __attribute__((address_space(1))) void*)g,
        (__attribute__((address_space(3))) void*)l, 16, 0, 0);
}

__device__ __forceinline__ float fast_tanh(float x) {
    float ax = fabsf(x);
    float e  = __expf(-2.f * ax);          // in (0,1], no overflow
    float t  = (1.f - e) / (1.f + e);
    return copysignf(t, x);
}

// ---------------------------------------------------------------------------
// Kernel CP (merged): [0, conv_blocks): V fp32->bf16 (grid-stride over N8);
// [conv_blocks, +256): Uw transpose -> UwT bf16; [+256, +384): whp.
// ---------------------------------------------------------------------------
__global__ void k_convprep(const float* __restrict__ V, __bf16* __restrict__ Vb,
                           const float* __restrict__ Uw, __bf16* __restrict__ UwT,
                           const float* __restrict__ h, const float* __restrict__ Ww,
                           const float* __restrict__ Wb, const float* __restrict__ Ub,
                           float* __restrict__ whp, int conv_blocks) {
    int t = threadIdx.x;  // 256
    if (blockIdx.x < (unsigned)conv_blocks) {
        int stride = conv_blocks * 256;
        for (int i = blockIdx.x * 256 + t; i < N8; i += stride) {
            const float4* s = reinterpret_cast<const float4*>(V + (size_t)i * 8);
            float4 x = s[0], y = s[1];
            bf16x8 w;
            w[0] = (__bf16)x.x; w[1] = (__bf16)x.y; w[2] = (__bf16)x.z; w[3] = (__bf16)x.w;
            w[4] = (__bf16)y.x; w[5] = (__bf16)y.y; w[6] = (__bf16)y.z; w[7] = (__bf16)y.w;
            reinterpret_cast<bf16x8*>(Vb)[i] = w;
        }
    } else if (blockIdx.x < (unsigned)conv_blocks + 256) {
        __shared__ __bf16 st[64][65];
        int bb = blockIdx.x - conv_blocks;
        int k0 = (bb & 31) * 64;
        int c0 = (bb >> 5) * 64;
#pragma unroll
        for (int i = 0; i < 16; ++i) {
            int lin = i * 256 + t;
            int kk = lin >> 6, cc = lin & 63;
            st[kk][cc] = (__bf16)Uw[(size_t)(k0 + kk) * ATT + c0 + cc];
        }
        __syncthreads();
#pragma unroll
        for (int i = 0; i < 16; ++i) {
            int lin = i * 256 + t;
            int cc = lin >> 6, kk = lin & 63;
            UwT[(size_t)(c0 + cc) * VDIM + k0 + kk] = st[kk][cc];
        }
    } else {
        __shared__ float hs[HDIM];
        int b = blockIdx.x - conv_blocks - 256;
        hs[t]       = h[(size_t)b * HDIM + t];
        hs[t + 256] = h[(size_t)b * HDIM + t + 256];
        __syncthreads();
        float acc0 = 0.f, acc1 = 0.f;
        for (int k = 0; k < HDIM; ++k) {
            float hv = hs[k];
            acc0 += hv * Ww[(size_t)k * ATT + t];
            acc1 += hv * Ww[(size_t)k * ATT + t + 256];
        }
        whp[(size_t)b * ATT + t]       = acc0 + Wb[t] + Ub[t];
        whp[(size_t)b * ATT + t + 256] = acc1 + Wb[t + 256] + Ub[t + 256];
    }
}

// ---------------------------------------------------------------------------
// Kernel G (main): 128x128 tile, BK=64, 4 waves, double-buffered with
// COUNTED vmcnt pipeline (depth 2): tile kt+1's 8 gload_lds stay in flight
// across tile kt's compute; waits vmcnt(8), drains to 0 only on the last
// iteration. Both operands XOR-swizzled (pre-swizzled source, linear
// gload_lds dest, swizzled ds_read). 784 blocks (XCD-bijective), 2/CU.
// ---------------------------------------------------------------------------
__global__ __launch_bounds__(256, 2) void k_scores128(
    const __bf16* __restrict__ Vb, const __bf16* __restrict__ UwT,
    const float* __restrict__ whp, const float* __restrict__ vw,
    float* __restrict__ e_part)
{
    __shared__ __align__(16) __bf16 As[2][BM1][BKK];   // 32 KB
    __shared__ __align__(16) __bf16 Bs[2][BN1][BKK];   // 32 KB
    __shared__ float red[2][BM1];

    int bid = blockIdx.x;
    int lid = (bid & 7) * (784 / 8) + (bid >> 3);
    int mtile = lid >> 2;         // 0..195
    int cc    = lid & 3;          // 0..3
    int m0 = mtile * BM1;
    int c0 = cc * BN1;
    int t    = threadIdx.x;
    int lane = t & 63;
    int wave = t >> 6;
    int wr = wave >> 1;
    int wc = wave & 1;

    f32x4 acc[4][4];
#pragma unroll
    for (int i = 0; i < 4; ++i)
#pragma unroll
        for (int j = 0; j < 4; ++j) acc[i][j] = (f32x4){0.f, 0.f, 0.f, 0.f};

    // staging: wave w round i covers rows [w*32+i*8, +8); LDS[row][c] holds
    // global chunk c^(row&7); dest linear -> source chunk = (lane&7)^lr.
    int lr  = lane >> 3;
    int csw = ((lane & 7) ^ lr) * 8;
    const __bf16* AgS = Vb  + (size_t)(m0 + wave * 32 + lr) * VDIM + csw;
    const __bf16* BgS = UwT + (size_t)(c0 + wave * 32 + lr) * VDIM + csw;
    __bf16* Al0 = &As[0][wave * 32 + lr][(lane & 7) * 8];
    __bf16* Bl0 = &Bs[0][wave * 32 + lr][(lane & 7) * 8];

    // 8 gload_lds per STAGE (4 A + 4 B) -> vmcnt(8) == one STAGE outstanding
#define STAGE(buf, kt)                                                          \
    do {                                                                        \
        _Pragma("unroll")                                                       \
        for (int i = 0; i < 4; ++i) {                                           \
            gload_lds16(AgS + (kt) * BKK + (size_t)i * 8 * VDIM,                \
                        Al0 + (buf) * (BM1 * BKK) + i * 8 * BKK);               \
            gload_lds16(BgS + (kt) * BKK + (size_t)i * 8 * VDIM,                \
                        Bl0 + (buf) * (BN1 * BKK) + i * 8 * BKK);               \
        }                                                                       \
    } while (0)

    int lcol = lane & 15;
    int lg4  = lane >> 4;
    int arow0 = wr * 64;
    int bcol0 = wc * 64;

    STAGE(0, 0);
    __builtin_amdgcn_sched_barrier(0);   // pin issue order: tile0 before tile1
    STAGE(1, 1);

    for (int kt = 0; kt < NT; ++kt) {
        int buf = kt & 1;
        if (kt < NT - 1) {
            asm volatile("s_waitcnt vmcnt(8)\n\ts_barrier" ::: "memory");
        } else {
            asm volatile("s_waitcnt vmcnt(0)\n\ts_barrier" ::: "memory");
        }
        __builtin_amdgcn_sched_barrier(0);

#pragma unroll
        for (int ks = 0; ks < 2; ++ks) {
            bf16x8 af[4], bfr[4];
#pragma unroll
            for (int i = 0; i < 4; ++i) {
                int row = arow0 + i * 16 + lcol;
                int ch  = ((ks * 4 + lg4) ^ (row & 7)) * 8;
                af[i] = *reinterpret_cast<const bf16x8*>(&As[buf][row][ch]);
            }
#pragma unroll
            for (int j = 0; j < 4; ++j) {
                int row = bcol0 + j * 16 + lcol;
                int ch  = ((ks * 4 + lg4) ^ (row & 7)) * 8;
                bfr[j] = *reinterpret_cast<const bf16x8*>(&Bs[buf][row][ch]);
            }
            __builtin_amdgcn_s_setprio(1);
#pragma unroll
            for (int i = 0; i < 4; ++i)
#pragma unroll
                for (int j = 0; j < 4; ++j)
                    acc[i][j] = __builtin_amdgcn_mfma_f32_16x16x32_bf16(af[i], bfr[j], acc[i][j], 0, 0, 0);
            __builtin_amdgcn_s_setprio(0);
        }

        __builtin_amdgcn_sched_barrier(0);
        asm volatile("s_barrier" ::: "memory");   // buf free: all waves consumed it
        if (kt + 2 < NT) STAGE(buf, kt + 2);
    }
#undef STAGE

    // ---- epilogue: rowsum over this block's 128 cols ----
    int lrow4 = lg4 * 4;
#pragma unroll
    for (int i = 0; i < 4; ++i) {
        float rs[4] = {0.f, 0.f, 0.f, 0.f};
#pragma unroll
        for (int j = 0; j < 4; ++j) {
            int col = c0 + wc * 64 + j * 16 + lcol;
            float vwv = vw[col];
#pragma unroll
            for (int r = 0; r < 4; ++r) {
                int m = m0 + wr * 64 + i * 16 + lrow4 + r;
                int b = m / N_;
                float x = acc[i][j][r] + whp[(size_t)b * ATT + col];
                rs[r] += fast_tanh(x) * vwv;
            }
        }
#pragma unroll
        for (int r = 0; r < 4; ++r) {
            float v = rs[r];
            v += __shfl_xor(v, 1);
            v += __shfl_xor(v, 2);
            v += __shfl_xor(v, 4);
            v += __shfl_xor(v, 8);
            if (lcol == 0)
                red[wc][wr * 64 + i * 16 + lrow4 + r] = v;
        }
    }
    __syncthreads();
    if (t < BM1)
        e_part[(size_t)cc * M_TOT + m0 + t] = red[0][t] + red[1][t];
}

// ---------------------------------------------------------------------------
// Kernel G (fallback, no-ws path): 128x128, fp32 A reg-staged, classic
// 2-phase drain barriers (R3-proven).
// ---------------------------------------------------------------------------
__global__ __launch_bounds__(256, 2) void k_scores_small(
    const float* __restrict__ Vf, const __bf16* __restrict__ UwT,
    const float* __restrict__ whp, const float* __restrict__ vw,
    float* __restrict__ e_part)
{
    __shared__ __align__(16) __bf16 As[2][BM1][BKK];
    __shared__ __align__(16) __bf16 Bs[2][BN1][BKK];
    __shared__ float red[2][BM1];

    int bid = blockIdx.x;
    int lid = (bid & 7) * (784 / 8) + (bid >> 3);
    int mtile = lid >> 2;
    int cc    = lid & 3;
    int m0 = mtile * BM1;
    int c0 = cc * BN1;
    int t    = threadIdx.x;
    int lane = t & 63;
    int wave = t >> 6;
    int wr = wave >> 1;
    int wc = wave & 1;

    f32x4 acc[4][4];
#pragma unroll
    for (int i = 0; i < 4; ++i)
#pragma unroll
        for (int j = 0; j < 4; ++j) acc[i][j] = (f32x4){0.f, 0.f, 0.f, 0.f};

    int lr  = lane >> 3;
    int csw = ((lane & 7) ^ lr) * 8;
    const __bf16* BgS = UwT + (size_t)(c0 + wave * 32 + lr) * VDIM + csw;
    __bf16* Bl0 = &Bs[0][wave * 32 + lr][(lane & 7) * 8];

    int ra = t >> 1;
    int ka = (t & 1) * 32;
    const float* Af = Vf + (size_t)(m0 + ra) * VDIM + ka;

#define STAGE1(buf, kt)                                                         \
    do {                                                                        \
        _Pragma("unroll")                                                       \
        for (int i = 0; i < 4; ++i)                                             \
            gload_lds16(BgS + (kt) * BKK + (size_t)i * 8 * VDIM,                \
                        Bl0 + (buf) * (BN1 * BKK) + i * 8 * BKK);               \
        const float4* src = reinterpret_cast<const float4*>(Af + (kt) * BKK);   \
        _Pragma("unroll")                                                       \
        for (int i = 0; i < 4; ++i) {                                           \
            float4 x = src[2 * i];                                              \
            float4 y = src[2 * i + 1];                                          \
            bf16x8 w;                                                           \
            w[0] = (__bf16)x.x; w[1] = (__bf16)x.y;                             \
            w[2] = (__bf16)x.z; w[3] = (__bf16)x.w;                             \
            w[4] = (__bf16)y.x; w[5] = (__bf16)y.y;                             \
            w[6] = (__bf16)y.z; w[7] = (__bf16)y.w;                             \
            int ch = (((t & 1) * 4 + i) ^ (ra & 7)) * 8;                        \
            *reinterpret_cast<bf16x8*>(&As[buf][ra][ch]) = w;                   \
        }                                                                       \
    } while (0)

    int lcol = lane & 15;
    int lg4  = lane >> 4;
    int arow0 = wr * 64;
    int bcol0 = wc * 64;

    STAGE1(0, 0);
    __syncthreads();

    for (int kt = 0; kt < NT; ++kt) {
        int buf = kt & 1;
        if (kt + 1 < NT) STAGE1(buf ^ 1, kt + 1);
#pragma unroll
        for (int ks = 0; ks < 2; ++ks) {
            bf16x8 af[4], bfr[4];
#pragma unroll
            for (int i = 0; i < 4; ++i) {
                int row = arow0 + i * 16 + lcol;
                int ch  = ((ks * 4 + lg4) ^ (row & 7)) * 8;
                af[i] = *reinterpret_cast<const bf16x8*>(&As[buf][row][ch]);
            }
#pragma unroll
            for (int j = 0; j < 4; ++j) {
                int row = bcol0 + j * 16 + lcol;
                int ch  = ((ks * 4 + lg4) ^ (row & 7)) * 8;
                bfr[j] = *reinterpret_cast<const bf16x8*>(&Bs[buf][row][ch]);
            }
#pragma unroll
            for (int i = 0; i < 4; ++i)
#pragma unroll
                for (int j = 0; j < 4; ++j)
                    acc[i][j] = __builtin_amdgcn_mfma_f32_16x16x32_bf16(af[i], bfr[j], acc[i][j], 0, 0, 0);
        }
        __syncthreads();
    }
#undef STAGE1

    int lrow4 = lg4 * 4;
#pragma unroll
    for (int i = 0; i < 4; ++i) {
        float rs[4] = {0.f, 0.f, 0.f, 0.f};
#pragma unroll
        for (int j = 0; j < 4; ++j) {
            int col = c0 + wc * 64 + j * 16 + lcol;
            float vwv = vw[col];
#pragma unroll
            for (int r = 0; r < 4; ++r) {
                int m = m0 + wr * 64 + i * 16 + lrow4 + r;
                int b = m / N_;
                float x = acc[i][j][r] + whp[(size_t)b * ATT + col];
                rs[r] += fast_tanh(x) * vwv;
            }
        }
#pragma unroll
        for (int r = 0; r < 4; ++r) {
            float v = rs[r];
            v += __shfl_xor(v, 1);
            v += __shfl_xor(v, 2);
            v += __shfl_xor(v, 4);
            v += __shfl_xor(v, 8);
            if (lcol == 0)
                red[wc][wr * 64 + i * 16 + lrow4 + r] = v;
        }
    }
    __syncthreads();
    if (t < BM1)
        e_part[(size_t)cc * M_TOT + m0 + t] = red[0][t] + red[1][t];
}

// ---------------------------------------------------------------------------
// Kernel S: softmax over N=196 per batch (npart partial score arrays)
// ---------------------------------------------------------------------------
__global__ void k_softmax(const float* __restrict__ e_part, const float* __restrict__ vb,
                          float* __restrict__ a_out, int npart) {
    int b = blockIdx.x;
    int t = threadIdx.x;  // 256
    __shared__ float sm[256];
    float ev = 0.f;
    float e  = -1e30f;
    if (t < N_) {
        int m = b * N_ + t;
        ev = vb[0];
        for (int p = 0; p < npart; ++p) ev += e_part[(size_t)p * M_TOT + m];
        e = ev;
    }
    sm[t] = e;
    __syncthreads();
    for (int s = 128; s > 0; s >>= 1) {
        if (t < s) sm[t] = fmaxf(sm[t], sm[t + s]);
        __syncthreads();
    }
    float mx = sm[0];
    __syncthreads();
    float ex = (t < N_) ? __expf(ev - mx) : 0.f;
    sm[t] = ex;
    __syncthreads();
    for (int s = 128; s > 0; s >>= 1) {
        if (t < s) sm[t] += sm[t + s];
        __syncthreads();
    }
    float inv = 1.f / sm[0];
    if (t < N_) a_out[(size_t)b * N_ + t] = ex * inv;
}

// ---------------------------------------------------------------------------
// Kernel C: ctx[b][v] = sum_n a[b][n] * V[b][n][v]
// ---------------------------------------------------------------------------
__global__ void k_ctx_bf(const __bf16* __restrict__ Vb, const float* __restrict__ a,
                         float* __restrict__ ctx) {
    int b  = blockIdx.x;   // 128
    int ch = blockIdx.y;   // 2 chunks of 1024 cols
    int t  = threadIdx.x;  // 128
    __shared__ float as_[N_];
    for (int i = t; i < N_; i += 128) as_[i] = a[(size_t)b * N_ + i];
    __syncthreads();
    int col = ch * 1024 + t * 8;
    const __bf16* Vp = Vb + (size_t)b * N_ * VDIM + col;
    float av[8] = {0.f, 0.f, 0.f, 0.f, 0.f, 0.f, 0.f, 0.f};
    for (int n = 0; n < N_; ++n) {
        bf16x8 v = *reinterpret_cast<const bf16x8*>(Vp + (size_t)n * VDIM);
        float an = as_[n];
#pragma unroll
        for (int j = 0; j < 8; ++j) av[j] += an * (float)v[j];
    }
    f32x4 lo = {av[0], av[1], av[2], av[3]};
    f32x4 hi = {av[4], av[5], av[6], av[7]};
    f32x4* dst = reinterpret_cast<f32x4*>(ctx + (size_t)b * VDIM + col);
    dst[0] = lo;
    dst[1] = hi;
}

__global__ void k_ctx_f32(const float* __restrict__ V, const float* __restrict__ a,
                          float* __restrict__ ctx) {
    int b  = blockIdx.x;
    int ch = blockIdx.y;
    int t  = threadIdx.x;  // 128
    __shared__ float as_[N_];
    for (int i = t; i < N_; i += 128) as_[i] = a[(size_t)b * N_ + i];
    __syncthreads();
    int col = ch * 512 + t * 4;
    const f32x4* Vp = reinterpret_cast<const f32x4*>(V + (size_t)b * N_ * VDIM + col);
    f32x4 accv = {0.f, 0.f, 0.f, 0.f};
    for (int n = 0; n < N_; ++n)
        accv += as_[n] * Vp[(size_t)n * (VDIM / 4)];
    *reinterpret_cast<f32x4*>(ctx + (size_t)b * VDIM + col) = accv;
}

// ---------------------------------------------------------------------------
extern "C" void kernel_launch(void* const* d_in, const int* in_sizes, int n_in,
                              void* d_out, int out_size, void* d_ws, size_t ws_size,
                              hipStream_t stream) {
    const float* h  = (const float*)d_in[0];
    const float* V  = (const float*)d_in[1];
    const float* Ww = (const float*)d_in[2];
    const float* Wb = (const float*)d_in[3];
    const float* Uw = (const float*)d_in[4];
    const float* Ub = (const float*)d_in[5];
    const float* vw = (const float*)d_in[6];
    const float* vb = (const float*)d_in[7];

    float* out     = (float*)d_out;
    float* ctx_out = out;                        // B*VDIM floats
    float* a_out   = out + (size_t)B_ * VDIM;    // B*N floats

    const size_t vb_bytes = (size_t)B_ * N_ * VDIM * sizeof(__bf16);  // ~103 MB
    const size_t tail     = 2u * 1024 * 1024 + 256 * 1024 + (size_t)4 * M_TOT * 4 + 4096;
    bool preconv = ws_size >= vb_bytes + tail;

    char*   ws   = (char*)d_ws;
    __bf16* Vb   = (__bf16*)ws;
    char*   rest = ws + (preconv ? vb_bytes : 0);
    __bf16* UwT   = (__bf16*)rest;
    float*  whp   = (float*)(rest + 2u * 1024 * 1024);
    float*  e_prt = (float*)(rest + 2u * 1024 * 1024 + 256 * 1024);

    int conv_blocks = preconv ? NCONVB : 0;
    k_convprep<<<dim3(conv_blocks + 256 + 128), 256, 0, stream>>>(
        V, Vb, Uw, UwT, h, Ww, Wb, Ub, whp, conv_blocks);
    if (preconv) {
        k_scores128<<<dim3(784), 256, 0, stream>>>(Vb, UwT, whp, vw, e_prt);
        k_softmax<<<dim3(B_), 256, 0, stream>>>(e_prt, vb, a_out, 4);
        k_ctx_bf<<<dim3(B_, 2), 128, 0, stream>>>(Vb, a_out, ctx_out);
    } else {
        k_scores_small<<<dim3(784), 256, 0, stream>>>(V, UwT, whp, vw, e_prt);
        k_softmax<<<dim3(B_), 256, 0, stream>>>(e_prt, vb, a_out, 4);
        k_ctx_f32<<<dim3(B_, 4), 128, 0, stream>>>(V, a_out, ctx_out);
    }
}